// Round 17
// baseline (262.878 us; speedup 1.0000x reference)
//
#include <hip/hip_runtime.h>
#include <hip/hip_bf16.h>
#include <math.h>

#define INPUT 2048
#define HIDDEN 128
#define BATCH 64
#define TSTEPS 512
#define RB 16

typedef _Float16 half_t;
typedef __attribute__((ext_vector_type(2))) _Float16 half2_t;
typedef __attribute__((ext_vector_type(8))) _Float16 f16x8;
typedef __attribute__((ext_vector_type(4))) float f32x4;

static __device__ __forceinline__ f16x8 as_f16x8(uint4 v) {
  return __builtin_bit_cast(f16x8, v);
}
static __device__ __forceinline__ unsigned int h2u(half2_t v) {
  return __builtin_bit_cast(unsigned int, v);
}
static __device__ __forceinline__ half2_t pkrtz(float a, float b) {
  return __builtin_bit_cast(half2_t, __builtin_amdgcn_cvt_pkrtz(a, b));
}
static __device__ __forceinline__ float h2f(unsigned short u) {
  return (float)__builtin_bit_cast(half_t, u);
}

// tanh(x) = 1 - 2/(e^{2x}+1); e^{2x} = 2^{x*2/ln2}. Saturates correctly.
static __device__ __forceinline__ float tanh_fast(float x) {
#if __has_builtin(__builtin_amdgcn_exp2f)
  const float e = __builtin_amdgcn_exp2f(x * 2.885390082f);
#else
  const float e = exp2f(x * 2.885390082f);
#endif
  return 1.f - 2.f * __builtin_amdgcn_rcpf(e + 1.f);
}

// LDS-visibility barrier (vmcnt not drained) — R16, kept (no cost, no harm).
static __device__ __forceinline__ void barrier_lds_only() {
  asm volatile("s_waitcnt lgkmcnt(0)" ::: "memory");
  __builtin_amdgcn_s_barrier();
}

// ---------------------------------------------------------------------------
// Prep: W_ih f32 -> Wg granule layout; W_hh f32 -> packed half2 (k-major).
// ---------------------------------------------------------------------------
__global__ __launch_bounds__(256) void prep_kernel(
    const float* __restrict__ W_ih, const float* __restrict__ W_hh,
    uint4* __restrict__ Wg, unsigned int* __restrict__ Whh2) {
  const int id = blockIdx.x * 256 + threadIdx.x;  // 32768 threads
  const int col = id & 127;
  const int kc = id >> 7;  // 0..255
  const float4 a = *(const float4*)(W_ih + (size_t)col * INPUT + kc * 8);
  const float4 b = *(const float4*)(W_ih + (size_t)col * INPUT + kc * 8 + 4);
  uint4 q = {h2u(pkrtz(a.x, a.y)), h2u(pkrtz(a.z, a.w)),
             h2u(pkrtz(b.x, b.y)), h2u(pkrtz(b.z, b.w))};
  Wg[(size_t)kc * 128 + col] = q;
  if (id < 8192) {
    float2 p = ((const float2*)W_hh)[id];
    half_t ha = (half_t)p.x, hb = (half_t)p.y;
    Whh2[id] = (unsigned int)__builtin_bit_cast(unsigned short, ha) |
               ((unsigned int)__builtin_bit_cast(unsigned short, hb) << 16);
  }
}

// ---------------------------------------------------------------------------
// GEMM: BK=128 (was 64). Doubles per-tile compute so the depth-2 register
// prefetch of x gives ~1000cy lead >= ~900cy HBM latency; halves barriers.
// A (x): LDS-staged f16, 32 KB double buffer. B (W): direct L2 granule loads
// per tile (no prefetch regs; one L2-latency stall/tile, absorbed by 2
// waves/SIMD). 256 thr = 4 waves (2 row-grp x 2 col-grp), 512 blocks.
// ---------------------------------------------------------------------------
#define GBM 64
#define GBK 128
#define GNKT (INPUT / GBK)  // 16

__global__ __launch_bounds__(256, 2) void gemm_xw_f16(
    const float* __restrict__ x, const uint4* __restrict__ Wg,
    const float* __restrict__ b_ih, const float* __restrict__ b_hh,
    half_t* __restrict__ xw) {
  __shared__ uint4 sA[2][16][64];  // [buf][kc][m]  32 KB

  const int tid = threadIdx.x;
  const int lane = tid & 63;
  const int w = tid >> 6;
  const int wr = w >> 1, wc = w & 1;
  const int block_row = blockIdx.x * GBM;
  const int kcl = lane >> 4;
  const int l15 = lane & 15;

  const int xm = tid & 63, xkq = tid >> 6;  // row, k-quarter (32 f32 each)
  const float* xsrc = x + (size_t)(block_row + xm) * INPUT + xkq * 32;

  f32x4 acc[2][4];
#pragma unroll
  for (int rt = 0; rt < 2; ++rt)
#pragma unroll
    for (int ct = 0; ct < 4; ++ct) acc[rt][ct] = (f32x4)0.f;

  float bias_c[4];
#pragma unroll
  for (int ct = 0; ct < 4; ++ct) {
    const int col = wc * 64 + ct * 16 + l15;
    bias_c[ct] = b_ih[col] + b_hh[col];
  }

  float4 xva[8], xvb[8];

  auto XLOAD = [&](int kt, float4* xv) {
    const float4* xs = (const float4*)(xsrc + kt * GBK);
#pragma unroll
    for (int j = 0; j < 8; ++j) xv[j] = xs[j];
  };
  auto XWRITE = [&](int bf, const float4* xv) {
#pragma unroll
    for (int g = 0; g < 4; ++g) {
      uint4 q = {h2u(pkrtz(xv[2 * g].x, xv[2 * g].y)),
                 h2u(pkrtz(xv[2 * g].z, xv[2 * g].w)),
                 h2u(pkrtz(xv[2 * g + 1].x, xv[2 * g + 1].y)),
                 h2u(pkrtz(xv[2 * g + 1].z, xv[2 * g + 1].w))};
      sA[bf][xkq * 4 + g][xm] = q;
    }
  };
  auto COMPUTE = [&](int bf, int kt) {
    uint4 af[4][2];
#pragma unroll
    for (int kf = 0; kf < 4; ++kf)
#pragma unroll
      for (int rt = 0; rt < 2; ++rt)
        af[kf][rt] = sA[bf][kf * 4 + kcl][wr * 32 + rt * 16 + l15];
    uint4 bb[4][4];
#pragma unroll
    for (int kf = 0; kf < 4; ++kf)
#pragma unroll
      for (int ct = 0; ct < 4; ++ct)
        bb[kf][ct] = Wg[(size_t)((kt * 16 + kf * 4 + kcl)) * 128 +
                        wc * 64 + ct * 16 + l15];
#pragma unroll
    for (int kf = 0; kf < 4; ++kf)
#pragma unroll
      for (int rt = 0; rt < 2; ++rt)
#pragma unroll
        for (int ct = 0; ct < 4; ++ct)
          acc[rt][ct] = __builtin_amdgcn_mfma_f32_16x16x32_f16(
              as_f16x8(af[kf][rt]), as_f16x8(bb[kf][ct]), acc[rt][ct], 0, 0, 0);
  };

  // prologue: x depth-2 (tiles 0,1 in regs), tile 0 staged
  XLOAD(0, xva);
  XLOAD(1, xvb);
  XWRITE(0, xva);
  __syncthreads();

#pragma unroll 1
  for (int kt = 0; kt < GNKT; kt += 2) {
    if (kt + 2 < GNKT) XLOAD(kt + 2, xva);  // tile kt already staged; reuse slot
    COMPUTE(0, kt);
    XWRITE(1, xvb);
    __syncthreads();
    if (kt + 3 < GNKT) XLOAD(kt + 3, xvb);
    COMPUTE(1, kt + 1);
    if (kt + 2 < GNKT) {
      XWRITE(0, xva);
      __syncthreads();
    }
  }

  // epilogue: C layout col = lane&15, row = (lane>>4)*4 + j
  const int rbase = block_row + wr * 32 + (lane >> 4) * 4;
#pragma unroll
  for (int rt = 0; rt < 2; ++rt)
#pragma unroll
    for (int ct = 0; ct < 4; ++ct) {
      const int col = wc * 64 + ct * 16 + l15;
#pragma unroll
      for (int j = 0; j < 4; ++j) {
        const int row = rbase + rt * 16 + j;
        xw[(size_t)row * HIDDEN + col] = (half_t)(acc[rt][ct][j] + bias_c[ct]);
      }
    }
}

// ---------------------------------------------------------------------------
// Recurrence via MFMA — R11/R16 structure (measured 186 us, stable across
// 4 structural attack attempts; treated as this decomposition's floor).
// ---------------------------------------------------------------------------
__global__ __launch_bounds__(256) void rnn_rec_mfma(
    const half_t* __restrict__ xw, const unsigned int* __restrict__ Whh2,
    const float* __restrict__ W_fc, const float* __restrict__ b_fc,
    float* __restrict__ out) {
  const int blk = blockIdx.x;    // 0..3
  const int tid = threadIdx.x;
  const int lane = tid & 63;
  const int w = tid >> 6;        // wave 0..3 -> h' tiles 2w, 2w+1
  const int bl = lane & 15;      // batch-local 0..15
  const int g = lane >> 4;       // k-group 0..3
  const int swz = (bl & 7) << 4; // LDS XOR swizzle (bits 4..6)

  __shared__ half_t st[2][RB][HIDDEN];  // 8 KB state double buffer
  __shared__ float red[256];

  uint4 afr[2][4];
#pragma unroll
  for (int mi = 0; mi < 2; ++mi)
#pragma unroll
    for (int kt = 0; kt < 4; ++kt)
      afr[mi][kt] = *(const uint4*)(Whh2 + ((size_t)((2 * w + mi) * 16 + bl)) * 64 +
                                    kt * 16 + g * 4);

#pragma unroll
  for (int i = 0; i < 4; ++i) ((unsigned int*)st)[tid + 256 * i] = 0u;
  __syncthreads();

  const half_t* xb0 = xw + ((size_t)(blk * RB + bl) * TSTEPS) * HIDDEN + w * 32 + g * 4;
  const half_t* xb1 = xb0 + 16;

  float hh[2][4];

  auto STEP = [&](const half_t* stR, half_t* stW, ushort4 xc0, ushort4 xc1) {
    uint4 bfr[4];
#pragma unroll
    for (int kt = 0; kt < 4; ++kt) {
      const int off = (bl * 256 + kt * 64 + g * 16) ^ swz;
      bfr[kt] = *(const uint4*)((const char*)stR + off);
    }
    f32x4 a0, a1;
    a0[0] = h2f(xc0.x); a0[1] = h2f(xc0.y); a0[2] = h2f(xc0.z); a0[3] = h2f(xc0.w);
    a1[0] = h2f(xc1.x); a1[1] = h2f(xc1.y); a1[2] = h2f(xc1.z); a1[3] = h2f(xc1.w);
#pragma unroll
    for (int kt = 0; kt < 4; ++kt) {
      a0 = __builtin_amdgcn_mfma_f32_16x16x32_f16(as_f16x8(afr[0][kt]),
                                                  as_f16x8(bfr[kt]), a0, 0, 0, 0);
      a1 = __builtin_amdgcn_mfma_f32_16x16x32_f16(as_f16x8(afr[1][kt]),
                                                  as_f16x8(bfr[kt]), a1, 0, 0, 0);
    }
#pragma unroll
    for (int j = 0; j < 4; ++j) {
      hh[0][j] = tanh_fast(a0[j]);
      hh[1][j] = tanh_fast(a1[j]);
    }
    uint2 p0 = {h2u(pkrtz(hh[0][0], hh[0][1])), h2u(pkrtz(hh[0][2], hh[0][3]))};
    uint2 p1 = {h2u(pkrtz(hh[1][0], hh[1][1])), h2u(pkrtz(hh[1][2], hh[1][3]))};
    const int w0 = (bl * 256 + (2 * w + 0) * 32 + g * 8) ^ swz;
    const int w1 = (bl * 256 + (2 * w + 1) * 32 + g * 8) ^ swz;
    *(uint2*)((char*)stW + w0) = p0;
    *(uint2*)((char*)stW + w1) = p1;
    barrier_lds_only();
  };

  ushort4 xA0 = *(const ushort4*)(xb0);
  ushort4 xA1 = *(const ushort4*)(xb1);
  ushort4 xB0 = *(const ushort4*)(xb0 + HIDDEN);
  ushort4 xB1 = *(const ushort4*)(xb1 + HIDDEN);

  for (int t2 = 0; t2 < TSTEPS; t2 += 2) {
    ushort4 c0 = xA0, c1 = xA1;
    xA0 = *(const ushort4*)(xb0 + (size_t)(t2 + 2) * HIDDEN);
    xA1 = *(const ushort4*)(xb1 + (size_t)(t2 + 2) * HIDDEN);
    STEP(&st[0][0][0], &st[1][0][0], c0, c1);

    ushort4 d0 = xB0, d1 = xB1;
    xB0 = *(const ushort4*)(xb0 + (size_t)(t2 + 3) * HIDDEN);
    xB1 = *(const ushort4*)(xb1 + (size_t)(t2 + 3) * HIDDEN);
    STEP(&st[1][0][0], &st[0][0][0], d0, d1);
  }

  const float4 wf0 = *(const float4*)&W_fc[(2 * w + 0) * 16 + g * 4];
  const float4 wf1 = *(const float4*)&W_fc[(2 * w + 1) * 16 + g * 4];
  float partial = hh[0][0] * wf0.x + hh[0][1] * wf0.y + hh[0][2] * wf0.z +
                  hh[0][3] * wf0.w + hh[1][0] * wf1.x + hh[1][1] * wf1.y +
                  hh[1][2] * wf1.z + hh[1][3] * wf1.w;
  red[tid] = partial;
  __syncthreads();
  if (tid < RB) {
    float s = b_fc[0];
#pragma unroll
    for (int q = 0; q < 16; ++q) s += red[q * 16 + tid];
    out[blk * RB + tid] = s;
  }
}

extern "C" void kernel_launch(void* const* d_in, const int* in_sizes, int n_in,
                              void* d_out, int out_size, void* d_ws, size_t ws_size,
                              hipStream_t stream) {
  const float* x    = (const float*)d_in[0];
  const float* W_ih = (const float*)d_in[1];
  const float* W_hh = (const float*)d_in[2];
  const float* b_ih = (const float*)d_in[3];
  const float* b_hh = (const float*)d_in[4];
  const float* W_fc = (const float*)d_in[5];
  const float* b_fc = (const float*)d_in[6];

  char* ws = (char*)d_ws;
  half_t*       xwf16 = (half_t*)ws;                                     // 8 MB
  uint4*        Wg    = (uint4*)(ws + (8u << 20));                       // 512 KB
  unsigned int* Whh2  = (unsigned int*)(ws + (8u << 20) + (512u << 10)); // 32 KB

  prep_kernel<<<128, 256, 0, stream>>>(W_ih, W_hh, Wg, Whh2);
  gemm_xw_f16<<<(BATCH * TSTEPS) / GBM, 256, 0, stream>>>(x, Wg, b_ih, b_hh, xwf16);
  rnn_rec_mfma<<<BATCH / RB, 256, 0, stream>>>(xwf16, Whh2, W_fc, b_fc, (float*)d_out);
}

// Round 18
// 244.775 us; speedup vs baseline: 1.0740x; 1.0740x over previous
//
#include <hip/hip_runtime.h>
#include <hip/hip_bf16.h>
#include <math.h>

#define INPUT 2048
#define HIDDEN 128
#define BATCH 64
#define TSTEPS 512
#define RB 16

typedef _Float16 half_t;
typedef __attribute__((ext_vector_type(2))) _Float16 half2_t;
typedef __attribute__((ext_vector_type(8))) _Float16 f16x8;
typedef __attribute__((ext_vector_type(4))) float f32x4;

static __device__ __forceinline__ f16x8 as_f16x8(uint4 v) {
  return __builtin_bit_cast(f16x8, v);
}
static __device__ __forceinline__ unsigned int h2u(half2_t v) {
  return __builtin_bit_cast(unsigned int, v);
}
static __device__ __forceinline__ half2_t pkrtz(float a, float b) {
  return __builtin_bit_cast(half2_t, __builtin_amdgcn_cvt_pkrtz(a, b));
}
static __device__ __forceinline__ float h2f(unsigned short u) {
  return (float)__builtin_bit_cast(half_t, u);
}

// tanh(x) = 1 - 2/(e^{2x}+1); e^{2x} = 2^{x*2/ln2}. Saturates correctly.
static __device__ __forceinline__ float tanh_fast(float x) {
#if __has_builtin(__builtin_amdgcn_exp2f)
  const float e = __builtin_amdgcn_exp2f(x * 2.885390082f);
#else
  const float e = exp2f(x * 2.885390082f);
#endif
  return 1.f - 2.f * __builtin_amdgcn_rcpf(e + 1.f);
}

// LDS-visibility barrier (vmcnt not drained) — measured cost-neutral (R16).
static __device__ __forceinline__ void barrier_lds_only() {
  asm volatile("s_waitcnt lgkmcnt(0)" ::: "memory");
  __builtin_amdgcn_s_barrier();
}

// ---------------------------------------------------------------------------
// Prep: W_ih f32 -> Wg granule layout; W_hh f32 -> packed half2 (k-major).
// ---------------------------------------------------------------------------
__global__ __launch_bounds__(256) void prep_kernel(
    const float* __restrict__ W_ih, const float* __restrict__ W_hh,
    uint4* __restrict__ Wg, unsigned int* __restrict__ Whh2) {
  const int id = blockIdx.x * 256 + threadIdx.x;  // 32768 threads
  const int col = id & 127;
  const int kc = id >> 7;  // 0..255
  const float4 a = *(const float4*)(W_ih + (size_t)col * INPUT + kc * 8);
  const float4 b = *(const float4*)(W_ih + (size_t)col * INPUT + kc * 8 + 4);
  uint4 q = {h2u(pkrtz(a.x, a.y)), h2u(pkrtz(a.z, a.w)),
             h2u(pkrtz(b.x, b.y)), h2u(pkrtz(b.z, b.w))};
  Wg[(size_t)kc * 128 + col] = q;
  if (id < 8192) {
    float2 p = ((const float2*)W_hh)[id];
    half_t ha = (half_t)p.x, hb = (half_t)p.y;
    Whh2[id] = (unsigned int)__builtin_bit_cast(unsigned short, ha) |
               ((unsigned int)__builtin_bit_cast(unsigned short, hb) << 16);
  }
}

// ---------------------------------------------------------------------------
// GEMM (R11 base, BK=64) with COALESCED x staging: thread t stages row t>>2,
// k-quarter t&3 -> 4 consecutive lanes read 4 consecutive float4 of one row
// (64B segments) instead of 64 lanes x 16B at 8KB stride (the R4-R17 map).
// LDS granule stride padded 64->65: write & frag-read b128 both 2-way (free).
// A: LDS-staged depth-2 register prefetch. B: direct L2 granule loads.
// ---------------------------------------------------------------------------
#define GBM 64
#define GBK 64
#define GNKT (INPUT / GBK)  // 32
#define SAP 65              // padded granule stride

__global__ __launch_bounds__(256) void gemm_xw_f16(
    const float* __restrict__ x, const uint4* __restrict__ Wg,
    const float* __restrict__ b_ih, const float* __restrict__ b_hh,
    half_t* __restrict__ xw) {
  __shared__ uint4 sA[2][8 * SAP];  // [buf][kc*SAP + m]  ~16.6 KB

  const int tid = threadIdx.x;
  const int lane = tid & 63;
  const int w = tid >> 6;
  const int wr = w >> 1, wc = w & 1;
  const int block_row = blockIdx.x * GBM;
  const int kcl = lane >> 4;
  const int l15 = lane & 15;

  // coalesced staging map: row = tid>>2, k-quarter (16 f32) = tid&3
  const int xm = tid >> 2, xkq = tid & 3;
  const float* xsrc = x + (size_t)(block_row + xm) * INPUT + xkq * 16;

  f32x4 acc[2][4];
#pragma unroll
  for (int rt = 0; rt < 2; ++rt)
#pragma unroll
    for (int ct = 0; ct < 4; ++ct) acc[rt][ct] = (f32x4)0.f;

  float bias_c[4];
#pragma unroll
  for (int ct = 0; ct < 4; ++ct) {
    const int col = wc * 64 + ct * 16 + l15;
    bias_c[ct] = b_ih[col] + b_hh[col];
  }

  float4 xva[4], xvb[4];
  uint4 br0[8], br1[8];

  auto XLOAD = [&](int kt, float4* xv) {
    const float4* xs = (const float4*)(xsrc + kt * GBK);
#pragma unroll
    for (int j = 0; j < 4; ++j) xv[j] = xs[j];
  };
  auto XWRITE = [&](int bf, const float4* xv) {
#pragma unroll
    for (int g = 0; g < 2; ++g) {
      uint4 q = {h2u(pkrtz(xv[2 * g].x, xv[2 * g].y)),
                 h2u(pkrtz(xv[2 * g].z, xv[2 * g].w)),
                 h2u(pkrtz(xv[2 * g + 1].x, xv[2 * g + 1].y)),
                 h2u(pkrtz(xv[2 * g + 1].z, xv[2 * g + 1].w))};
      sA[bf][(xkq * 2 + g) * SAP + xm] = q;
    }
  };
  auto BLOAD = [&](int kt, uint4* bb) {
#pragma unroll
    for (int kf = 0; kf < 2; ++kf)
#pragma unroll
      for (int ct = 0; ct < 4; ++ct)
        bb[kf * 4 + ct] =
            Wg[(size_t)(kt * 8 + kf * 4 + kcl) * 128 + wc * 64 + ct * 16 + l15];
  };
  auto COMPUTE = [&](int bf, const uint4* bb) {
    uint4 af[2][2];
#pragma unroll
    for (int kf = 0; kf < 2; ++kf)
#pragma unroll
      for (int rt = 0; rt < 2; ++rt)
        af[kf][rt] = sA[bf][(kf * 4 + kcl) * SAP + wr * 32 + rt * 16 + l15];
#pragma unroll
    for (int kf = 0; kf < 2; ++kf)
#pragma unroll
      for (int rt = 0; rt < 2; ++rt)
#pragma unroll
        for (int ct = 0; ct < 4; ++ct)
          acc[rt][ct] = __builtin_amdgcn_mfma_f32_16x16x32_f16(
              as_f16x8(af[kf][rt]), as_f16x8(bb[kf * 4 + ct]), acc[rt][ct], 0, 0, 0);
  };

  XLOAD(0, xva);
  XLOAD(1, xvb);
  BLOAD(0, br0);
  XWRITE(0, xva);
  __syncthreads();

#pragma unroll 1
  for (int kt = 0; kt < GNKT; kt += 2) {
    BLOAD(kt + 1, br1);
    if (kt + 2 < GNKT) XLOAD(kt + 2, xva);
    COMPUTE(0, br0);
    XWRITE(1, xvb);
    __syncthreads();
    if (kt + 2 < GNKT) BLOAD(kt + 2, br0);
    if (kt + 3 < GNKT) XLOAD(kt + 3, xvb);
    COMPUTE(1, br1);
    if (kt + 2 < GNKT) {
      XWRITE(0, xva);
      __syncthreads();
    }
  }

  const int rbase = block_row + wr * 32 + (lane >> 4) * 4;
#pragma unroll
  for (int rt = 0; rt < 2; ++rt)
#pragma unroll
    for (int ct = 0; ct < 4; ++ct) {
      const int col = wc * 64 + ct * 16 + l15;
#pragma unroll
      for (int j = 0; j < 4; ++j) {
        const int row = rbase + rt * 16 + j;
        xw[(size_t)row * HIDDEN + col] = (half_t)(acc[rt][ct][j] + bias_c[ct]);
      }
    }
}

// ---------------------------------------------------------------------------
// Recurrence via MFMA — R11/R16 structure (186 us, stable across 5 attacks;
// treated as this decomposition's floor).
// ---------------------------------------------------------------------------
__global__ __launch_bounds__(256) void rnn_rec_mfma(
    const half_t* __restrict__ xw, const unsigned int* __restrict__ Whh2,
    const float* __restrict__ W_fc, const float* __restrict__ b_fc,
    float* __restrict__ out) {
  const int blk = blockIdx.x;    // 0..3
  const int tid = threadIdx.x;
  const int lane = tid & 63;
  const int w = tid >> 6;        // wave 0..3 -> h' tiles 2w, 2w+1
  const int bl = lane & 15;      // batch-local 0..15
  const int g = lane >> 4;       // k-group 0..3
  const int swz = (bl & 7) << 4; // LDS XOR swizzle (bits 4..6)

  __shared__ half_t st[2][RB][HIDDEN];  // 8 KB state double buffer
  __shared__ float red[256];

  uint4 afr[2][4];
#pragma unroll
  for (int mi = 0; mi < 2; ++mi)
#pragma unroll
    for (int kt = 0; kt < 4; ++kt)
      afr[mi][kt] = *(const uint4*)(Whh2 + ((size_t)((2 * w + mi) * 16 + bl)) * 64 +
                                    kt * 16 + g * 4);

#pragma unroll
  for (int i = 0; i < 4; ++i) ((unsigned int*)st)[tid + 256 * i] = 0u;
  __syncthreads();

  const half_t* xb0 = xw + ((size_t)(blk * RB + bl) * TSTEPS) * HIDDEN + w * 32 + g * 4;
  const half_t* xb1 = xb0 + 16;

  float hh[2][4];

  auto STEP = [&](const half_t* stR, half_t* stW, ushort4 xc0, ushort4 xc1) {
    uint4 bfr[4];
#pragma unroll
    for (int kt = 0; kt < 4; ++kt) {
      const int off = (bl * 256 + kt * 64 + g * 16) ^ swz;
      bfr[kt] = *(const uint4*)((const char*)stR + off);
    }
    f32x4 a0, a1;
    a0[0] = h2f(xc0.x); a0[1] = h2f(xc0.y); a0[2] = h2f(xc0.z); a0[3] = h2f(xc0.w);
    a1[0] = h2f(xc1.x); a1[1] = h2f(xc1.y); a1[2] = h2f(xc1.z); a1[3] = h2f(xc1.w);
#pragma unroll
    for (int kt = 0; kt < 4; ++kt) {
      a0 = __builtin_amdgcn_mfma_f32_16x16x32_f16(as_f16x8(afr[0][kt]),
                                                  as_f16x8(bfr[kt]), a0, 0, 0, 0);
      a1 = __builtin_amdgcn_mfma_f32_16x16x32_f16(as_f16x8(afr[1][kt]),
                                                  as_f16x8(bfr[kt]), a1, 0, 0, 0);
    }
#pragma unroll
    for (int j = 0; j < 4; ++j) {
      hh[0][j] = tanh_fast(a0[j]);
      hh[1][j] = tanh_fast(a1[j]);
    }
    uint2 p0 = {h2u(pkrtz(hh[0][0], hh[0][1])), h2u(pkrtz(hh[0][2], hh[0][3]))};
    uint2 p1 = {h2u(pkrtz(hh[1][0], hh[1][1])), h2u(pkrtz(hh[1][2], hh[1][3]))};
    const int w0 = (bl * 256 + (2 * w + 0) * 32 + g * 8) ^ swz;
    const int w1 = (bl * 256 + (2 * w + 1) * 32 + g * 8) ^ swz;
    *(uint2*)((char*)stW + w0) = p0;
    *(uint2*)((char*)stW + w1) = p1;
    barrier_lds_only();
  };

  ushort4 xA0 = *(const ushort4*)(xb0);
  ushort4 xA1 = *(const ushort4*)(xb1);
  ushort4 xB0 = *(const ushort4*)(xb0 + HIDDEN);
  ushort4 xB1 = *(const ushort4*)(xb1 + HIDDEN);

  for (int t2 = 0; t2 < TSTEPS; t2 += 2) {
    ushort4 c0 = xA0, c1 = xA1;
    xA0 = *(const ushort4*)(xb0 + (size_t)(t2 + 2) * HIDDEN);
    xA1 = *(const ushort4*)(xb1 + (size_t)(t2 + 2) * HIDDEN);
    STEP(&st[0][0][0], &st[1][0][0], c0, c1);

    ushort4 d0 = xB0, d1 = xB1;
    xB0 = *(const ushort4*)(xb0 + (size_t)(t2 + 3) * HIDDEN);
    xB1 = *(const ushort4*)(xb1 + (size_t)(t2 + 3) * HIDDEN);
    STEP(&st[1][0][0], &st[0][0][0], d0, d1);
  }

  const float4 wf0 = *(const float4*)&W_fc[(2 * w + 0) * 16 + g * 4];
  const float4 wf1 = *(const float4*)&W_fc[(2 * w + 1) * 16 + g * 4];
  float partial = hh[0][0] * wf0.x + hh[0][1] * wf0.y + hh[0][2] * wf0.z +
                  hh[0][3] * wf0.w + hh[1][0] * wf1.x + hh[1][1] * wf1.y +
                  hh[1][2] * wf1.z + hh[1][3] * wf1.w;
  red[tid] = partial;
  __syncthreads();
  if (tid < RB) {
    float s = b_fc[0];
#pragma unroll
    for (int q = 0; q < 16; ++q) s += red[q * 16 + tid];
    out[blk * RB + tid] = s;
  }
}

extern "C" void kernel_launch(void* const* d_in, const int* in_sizes, int n_in,
                              void* d_out, int out_size, void* d_ws, size_t ws_size,
                              hipStream_t stream) {
  const float* x    = (const float*)d_in[0];
  const float* W_ih = (const float*)d_in[1];
  const float* W_hh = (const float*)d_in[2];
  const float* b_ih = (const float*)d_in[3];
  const float* b_hh = (const float*)d_in[4];
  const float* W_fc = (const float*)d_in[5];
  const float* b_fc = (const float*)d_in[6];

  char* ws = (char*)d_ws;
  half_t*       xwf16 = (half_t*)ws;                                     // 8 MB
  uint4*        Wg    = (uint4*)(ws + (8u << 20));                       // 512 KB
  unsigned int* Whh2  = (unsigned int*)(ws + (8u << 20) + (512u << 10)); // 32 KB

  prep_kernel<<<128, 256, 0, stream>>>(W_ih, W_hh, Wg, Whh2);
  gemm_xw_f16<<<(BATCH * TSTEPS) / GBM, 256, 0, stream>>>(x, Wg, b_ih, b_hh, xwf16);
  rnn_rec_mfma<<<BATCH / RB, 256, 0, stream>>>(xwf16, Whh2, W_fc, b_fc, (float*)d_out);
}